// Round 3
// baseline (149.159 us; speedup 1.0000x reference)
//
#include <hip/hip_runtime.h>
#include <math.h>

#define N_TOK 8192
#define DIM   2048
#define NE    64
#define TOPK  4
#define THETA 2e-3f
#define TPB   32                      /* tokens per k_main block */
#define NBLK  (N_TOK / TPB)           /* 256 */
#define HSTR  16                      /* hist padding: 1 counter per 64B line */

typedef short bf16x8 __attribute__((ext_vector_type(8)));
typedef float f32x4  __attribute__((ext_vector_type(4)));

// ---- workspace layout (float offsets) ----
#define OFF_LOGITS 0                          /* N_TOK*NE = 524288 */
#define OFF_MAXV   (OFF_LOGITS + N_TOK * NE)
#define OFF_DENOM  (OFF_MAXV + N_TOK)
#define OFF_HIST   (OFF_DENOM + N_TOK)        /* int, NE*HSTR = 1024 */
#define OFF_WT     (OFF_HIST + NE * HSTR)     /* NE*DIM fp32 transposed */
#define OFF_WTMP   (OFF_WT + NE * DIM)        /* N_TOK*TOPK */

// pack 2 fp32 -> 2 truncated bf16 (hi) and 2 truncated bf16 of residual (lo)
__device__ inline void cvt2(float a, float b, unsigned& hi, unsigned& lo) {
    const unsigned ua = __float_as_uint(a), ub = __float_as_uint(b);
    hi = __builtin_amdgcn_perm(ub, ua, 0x07060302u);   // [a_hi16, b_hi16]
    const float ra = a - __uint_as_float(ua & 0xFFFF0000u);
    const float rb = b - __uint_as_float(ub & 0xFFFF0000u);
    lo = __builtin_amdgcn_perm(__float_as_uint(rb), __float_as_uint(ra), 0x07060302u);
}

union FragU { unsigned u[4]; bf16x8 v; uint4 q; };

__device__ inline void make_frags(const float4& p, const float4& q,
                                  bf16x8& hi, bf16x8& lo) {
    FragU H, L;
    cvt2(p.x, p.y, H.u[0], L.u[0]);
    cvt2(p.z, p.w, H.u[1], L.u[1]);
    cvt2(q.x, q.y, H.u[2], L.u[2]);
    cvt2(q.z, q.w, H.u[3], L.u[3]);
    hi = H.v; lo = L.v;
}

// wt fp32 transpose [k][e] (for exact recompute) + hist zero.
__global__ __launch_bounds__(256)
void k_wc(const float* __restrict__ W, float* __restrict__ wt,
          int* __restrict__ hist) {
    const int t = blockIdx.x * 256 + threadIdx.x;     // 0..16383
    if (t < NE * HSTR) hist[t] = 0;
    const int l  = t & 63;
    const int grp = t >> 6;                           // 0..255
    const int nt = grp & 3;
    const int kc = grp >> 2;
    const int e  = nt * 16 + (l & 15);
    const int k0 = kc * 32 + (l >> 4) * 8;

    const float4 p = *reinterpret_cast<const float4*>(W + (size_t)e * DIM + k0);
    const float4 q = *reinterpret_cast<const float4*>(W + (size_t)e * DIM + k0 + 4);
    wt[(size_t)(k0 + 0) * NE + e] = p.x;
    wt[(size_t)(k0 + 1) * NE + e] = p.y;
    wt[(size_t)(k0 + 2) * NE + e] = p.z;
    wt[(size_t)(k0 + 3) * NE + e] = p.w;
    wt[(size_t)(k0 + 4) * NE + e] = q.x;
    wt[(size_t)(k0 + 5) * NE + e] = q.y;
    wt[(size_t)(k0 + 6) * NE + e] = q.z;
    wt[(size_t)(k0 + 7) * NE + e] = q.w;
}

// Barrier-free split-bf16 MFMA GEMM (A and B direct from global, in-register
// cvt) + stats + in-block exact recompute + histogram + fast-path out write.
// 512 thr (8 waves), 32 tokens/block, 256 blocks. Wave w owns k-slice w*32
// of each 256-k window; no LDS / no __syncthreads in the K loop.
__global__ __launch_bounds__(512, 2)
void k_main(const float* __restrict__ x, const float* __restrict__ W,
            const float* __restrict__ bias, const float* __restrict__ wt,
            float* __restrict__ logits, float* __restrict__ maxv,
            float* __restrict__ denomv, int* __restrict__ hist,
            float* __restrict__ out) {
    __shared__ float red[8][TPB][68];                 // 69632 B
    __shared__ float lbuf[TPB][68];                   //  8704 B
    __shared__ int   selS[TPB];
    __shared__ float wS[TPB];
    __shared__ short flagIdx[TPB];
    __shared__ int   flagCnt;

    const int tid = threadIdx.x;
    const int w   = tid >> 6;            // wave 0..7
    const int l   = tid & 63;
    const int t0  = blockIdx.x * TPB;
    const int m   = l & 15;              // token-in-tile (A) / expert-low (B)
    const int g   = l >> 4;              // k-octet group

    if (tid == 0) flagCnt = 0;

    // A: token rows t0+m (tile0), t0+16+m (tile1); k = win*256 + w*32 + g*8
    const float* aP0 = x + (size_t)(t0 + m) * DIM + w * 32 + g * 8;
    const float* aP1 = aP0 + (size_t)16 * DIM;
    // B: W[e][k], e = nt*16 + m
    const float* bP  = W + (size_t)m * DIM + w * 32 + g * 8;

    f32x4 accA[2][4], accB[2][4];
    #pragma unroll
    for (int t = 0; t < 2; ++t)
        #pragma unroll
        for (int nt = 0; nt < 4; ++nt)
            #pragma unroll
            for (int r = 0; r < 4; ++r) { accA[t][nt][r] = 0.0f; accB[t][nt][r] = 0.0f; }

    float4 cA[2][4], cB[2][8];
    // prologue: load window 0 into buffer 0
    cA[0][0] = *reinterpret_cast<const float4*>(aP0);
    cA[0][1] = *reinterpret_cast<const float4*>(aP0 + 4);
    cA[0][2] = *reinterpret_cast<const float4*>(aP1);
    cA[0][3] = *reinterpret_cast<const float4*>(aP1 + 4);
    #pragma unroll
    for (int nt = 0; nt < 4; ++nt) {
        cB[0][nt * 2 + 0] = *reinterpret_cast<const float4*>(bP + (size_t)nt * 16 * DIM);
        cB[0][nt * 2 + 1] = *reinterpret_cast<const float4*>(bP + (size_t)nt * 16 * DIM + 4);
    }

    #pragma unroll
    for (int win = 0; win < 8; ++win) {
        const int cur = win & 1, nxt = cur ^ 1;
        if (win < 7) {
            const int ko = (win + 1) * 256;
            cA[nxt][0] = *reinterpret_cast<const float4*>(aP0 + ko);
            cA[nxt][1] = *reinterpret_cast<const float4*>(aP0 + ko + 4);
            cA[nxt][2] = *reinterpret_cast<const float4*>(aP1 + ko);
            cA[nxt][3] = *reinterpret_cast<const float4*>(aP1 + ko + 4);
            #pragma unroll
            for (int nt = 0; nt < 4; ++nt) {
                cB[nxt][nt * 2 + 0] =
                    *reinterpret_cast<const float4*>(bP + (size_t)nt * 16 * DIM + ko);
                cB[nxt][nt * 2 + 1] =
                    *reinterpret_cast<const float4*>(bP + (size_t)nt * 16 * DIM + ko + 4);
            }
        }

        bf16x8 bh[4], bl[4];
        #pragma unroll
        for (int nt = 0; nt < 4; ++nt)
            make_frags(cB[cur][nt * 2], cB[cur][nt * 2 + 1], bh[nt], bl[nt]);

        #pragma unroll
        for (int t = 0; t < 2; ++t) {
            bf16x8 ah, al;
            make_frags(cA[cur][t * 2], cA[cur][t * 2 + 1], ah, al);
            #pragma unroll
            for (int nt = 0; nt < 4; ++nt) {
                accA[t][nt] = __builtin_amdgcn_mfma_f32_16x16x32_bf16(ah, bh[nt], accA[t][nt], 0, 0, 0);
                accB[t][nt] = __builtin_amdgcn_mfma_f32_16x16x32_bf16(al, bh[nt], accB[t][nt], 0, 0, 0);
            }
            #pragma unroll
            for (int nt = 0; nt < 4; ++nt)
                accB[t][nt] = __builtin_amdgcn_mfma_f32_16x16x32_bf16(ah, bl[nt], accB[t][nt], 0, 0, 0);
        }
    }

    #pragma unroll
    for (int t = 0; t < 2; ++t)
        #pragma unroll
        for (int nt = 0; nt < 4; ++nt)
            #pragma unroll
            for (int r = 0; r < 4; ++r)
                red[w][t * 16 + g * 4 + r][nt * 16 + m] = accA[t][nt][r] + accB[t][nt][r];
    __syncthreads();

    for (int e2 = tid; e2 < TPB * NE; e2 += 512) {
        const int t = e2 >> 6, e = e2 & 63;
        float s = red[0][t][e];
        #pragma unroll
        for (int ww = 1; ww < 8; ++ww) s += red[ww][t][e];
        s += bias[e];
        logits[(size_t)(t0 + t) * NE + e] = s;
        lbuf[t][e] = s;
    }
    __syncthreads();

    #pragma unroll
    for (int tt = 0; tt < 4; ++tt) {
        const int t = w * 4 + tt;
        const float lv = lbuf[t][l];
        float v1 = lv; int i1 = l; float v2 = -INFINITY;
        #pragma unroll
        for (int off = 32; off; off >>= 1) {
            const float ov1 = __shfl_xor(v1, off);
            const int   oi1 = __shfl_xor(i1, off);
            const float ov2 = __shfl_xor(v2, off);
            if (ov1 > v1 || (ov1 == v1 && oi1 < i1)) {
                v2 = fmaxf(v1, ov2); v1 = ov1; i1 = oi1;
            } else {
                v2 = fmaxf(v2, ov1);
            }
        }
        float s = expf(lv - v1);
        #pragma unroll
        for (int off = 32; off; off >>= 1) s += __shfl_xor(s, off);
        if (l == 0) {
            const int row = t0 + t;
            maxv[row]   = v1;
            denomv[row] = s;
            selS[t]     = i1;
            wS[t]       = 1.0f / s;
            if (v1 - v2 < THETA) {
                const int ix = atomicAdd(&flagCnt, 1);
                flagIdx[ix] = (short)t;
            }
        }
    }
    __syncthreads();

    // ---- in-block exact fp32 recompute for flagged (near-tie) tokens ----
    const int nf = flagCnt;
    for (int fi = 0; fi < nf; ++fi) {
        const int tl  = flagIdx[fi];
        const int row = t0 + tl;
        // 8 waves split K: wave w covers k in [w*256, w*256+256); lane = expert
        const float* xr = x + (size_t)row * DIM + w * 256;
        const float* wb = wt + (size_t)(w * 256) * NE + l;
        float a0 = 0.0f, a1 = 0.0f;
        #pragma unroll 4
        for (int k = 0; k < 256; k += 8) {
            const float4 x0 = *reinterpret_cast<const float4*>(xr + k);
            const float4 x1 = *reinterpret_cast<const float4*>(xr + k + 4);
            a0 = fmaf(x0.x, wb[(size_t)(k + 0) * NE], a0);
            a0 = fmaf(x0.y, wb[(size_t)(k + 1) * NE], a0);
            a0 = fmaf(x0.z, wb[(size_t)(k + 2) * NE], a0);
            a0 = fmaf(x0.w, wb[(size_t)(k + 3) * NE], a0);
            a1 = fmaf(x1.x, wb[(size_t)(k + 4) * NE], a1);
            a1 = fmaf(x1.y, wb[(size_t)(k + 5) * NE], a1);
            a1 = fmaf(x1.z, wb[(size_t)(k + 6) * NE], a1);
            a1 = fmaf(x1.w, wb[(size_t)(k + 7) * NE], a1);
        }
        red[w][0][l] = a0 + a1;
        __syncthreads();
        if (w == 0) {
            float lg = bias[l];
            #pragma unroll
            for (int s2 = 0; s2 < 8; ++s2) lg += red[s2][0][l];
            logits[(size_t)row * NE + l] = lg;
            float v = lg; int idx = l;
            #pragma unroll
            for (int off = 32; off; off >>= 1) {
                const float ov = __shfl_xor(v, off);
                const int   oi = __shfl_xor(idx, off);
                if (ov > v || (ov == v && oi < idx)) { v = ov; idx = oi; }
            }
            float p = expf(lg - v);
            #pragma unroll
            for (int off = 32; off; off >>= 1) p += __shfl_xor(p, off);
            if (l == 0) {
                maxv[row]   = v;
                denomv[row] = p;
                selS[tl]    = idx;
                wS[tl]      = 1.0f / p;
            }
        }
        __syncthreads();
    }

    // ---- selection histogram: wave 0, lane = expert; padded counters ----
    if (w == 0) {
        int cnt = 0;
        #pragma unroll
        for (int t = 0; t < TPB; ++t) cnt += (selS[t] == l) ? 1 : 0;
        if (cnt) atomicAdd(&hist[l * HSTR], cnt);
    }

    // ---- fast-path out write (k_decide fixes up only on capacity overflow) --
    if (tid < TPB) {
        const int row = t0 + tid;
        const float se = (float)selS[tid];
        const float wv = wS[tid];
        const float wn = wv / (4.0f * wv + 1e-8f);
        *reinterpret_cast<float4*>(out + (size_t)row * 4) = make_float4(se, se, se, se);
        *reinterpret_cast<float4*>(out + (size_t)N_TOK * TOPK + (size_t)row * 4) =
            make_float4(wn, wn, wn, wn);
    }
}

// capacity check from hist; out already holds the fast path. Single block:
// if any expert over capacity, run the exact serial fallback.
__global__ __launch_bounds__(256)
void k_decide(const int* __restrict__ hist, const float* __restrict__ logits,
              const float* __restrict__ maxv, const float* __restrict__ denomv,
              const int* __restrict__ tc, float* __restrict__ out,
              float* __restrict__ wtmp) {
    __shared__ int flagS;
    const int tid = threadIdx.x;
    const int cap = tc[0] / TOPK;
    if (tid < NE) {
        const bool bad = (TOPK * hist[tid * HSTR] > cap);
        const unsigned long long mm = __ballot(bad);
        if (tid == 0) flagS = (mm == 0ull) ? 1 : 0;
    }
    __syncthreads();
    if (flagS) return;                 // fast path already written by k_main

    if (tid < 64) {
        const int e = tid;
        int rem = cap;
        for (int k = 0; k < TOPK; ++k) {
            for (int b = 0; b < N_TOK; ++b) {
                const float lg = logits[(size_t)b * NE + e];
                float v = (rem > 0) ? lg : -INFINITY;
                int idx = e;
                #pragma unroll
                for (int off = 32; off; off >>= 1) {
                    const float ov = __shfl_xor(v, off);
                    const int   oi = __shfl_xor(idx, off);
                    if (ov > v || (ov == v && oi < idx)) { v = ov; idx = oi; }
                }
                const bool ok = (v != -INFINITY);
                if (ok && e == idx) rem -= 1;
                const float lc = __shfl(lg, idx);
                if (e == 0) {
                    out[(size_t)b * TOPK + k]  = ok ? (float)idx : -1.0f;
                    wtmp[(size_t)b * TOPK + k] = ok ? expf(lc - maxv[b]) / denomv[b] : 0.0f;
                }
            }
        }
    }
    __syncthreads();
    for (int b = tid; b < N_TOK; b += 256) {
        const float w0 = wtmp[b * 4 + 0], w1_ = wtmp[b * 4 + 1];
        const float w2 = wtmp[b * 4 + 2], w3 = wtmp[b * 4 + 3];
        const float s = ((w0 + w1_) + w2) + w3 + 1e-8f;
        out[N_TOK * TOPK + b * 4 + 0] = w0 / s;
        out[N_TOK * TOPK + b * 4 + 1] = w1_ / s;
        out[N_TOK * TOPK + b * 4 + 2] = w2 / s;
        out[N_TOK * TOPK + b * 4 + 3] = w3 / s;
    }
}

extern "C" void kernel_launch(void* const* d_in, const int* in_sizes, int n_in,
                              void* d_out, int out_size, void* d_ws, size_t ws_size,
                              hipStream_t stream) {
    const float* x    = (const float*)d_in[0];
    const float* W    = (const float*)d_in[1];
    const float* bias = (const float*)d_in[2];
    const int*   tc   = (const int*)d_in[3];

    float* ws       = (float*)d_ws;
    float* logits   = ws + OFF_LOGITS;
    float* maxv     = ws + OFF_MAXV;
    float* denomv   = ws + OFF_DENOM;
    int*   hist     = (int*)(ws + OFF_HIST);
    float* wt       = ws + OFF_WT;
    float* wtmp     = ws + OFF_WTMP;
    float* out      = (float*)d_out;

    k_wc<<<NE * DIM / 8 / 256, 256, 0, stream>>>(W, wt, hist);
    k_main<<<NBLK, 512, 0, stream>>>(x, W, bias, wt, logits, maxv, denomv,
                                     hist, out);
    k_decide<<<1, 256, 0, stream>>>(hist, logits, maxv, denomv, tc, out, wtmp);
}

// Round 5
// 131.036 us; speedup vs baseline: 1.1383x; 1.1383x over previous
//
#include <hip/hip_runtime.h>
#include <math.h>

#define N_TOK 8192
#define DIM   2048
#define NE    64
#define TOPK  4
#define THETA 2e-3f
#define TPB   16                      /* tokens per k_main block */
#define NBLK  (N_TOK / TPB)           /* 512 */
#define HSTR  16                      /* hist padding: 1 counter per 64B line */

typedef short bf16x8 __attribute__((ext_vector_type(8)));
typedef float f32x4  __attribute__((ext_vector_type(4)));

// ---- workspace layout (float offsets) ----
#define OFF_LOGITS 0                          /* N_TOK*NE = 524288 */
#define OFF_MAXV   (OFF_LOGITS + N_TOK * NE)
#define OFF_DENOM  (OFF_MAXV + N_TOK)
#define OFF_HIST   (OFF_DENOM + N_TOK)        /* int, NE*HSTR = 1024 */
#define OFF_WH     (OFF_HIST + NE * HSTR)     /* NE*DIM bf16, frag-packed */
#define OFF_WL     (OFF_WH + NE * DIM / 2)
#define OFF_WT     (OFF_WL + NE * DIM / 2)    /* NE*DIM fp32 transposed */
#define OFF_WTMP   (OFF_WT + NE * DIM)        /* N_TOK*TOPK */

// pack 2 fp32 -> 2 truncated bf16 (hi) and 2 truncated bf16 of residual (lo)
__device__ inline void cvt2(float a, float b, unsigned& hi, unsigned& lo) {
    const unsigned ua = __float_as_uint(a), ub = __float_as_uint(b);
    hi = __builtin_amdgcn_perm(ub, ua, 0x07060302u);   // [a_hi16, b_hi16]
    const float ra = a - __uint_as_float(ua & 0xFFFF0000u);
    const float rb = b - __uint_as_float(ub & 0xFFFF0000u);
    lo = __builtin_amdgcn_perm(__float_as_uint(rb), __float_as_uint(ra), 0x07060302u);
}

union FragU { unsigned u[4]; bf16x8 v; uint4 q; };

__device__ inline void make_frags(const float4& p, const float4& q,
                                  bf16x8& hi, bf16x8& lo) {
    FragU H, L;
    cvt2(p.x, p.y, H.u[0], L.u[0]);
    cvt2(p.z, p.w, H.u[1], L.u[1]);
    cvt2(q.x, q.y, H.u[2], L.u[2]);
    cvt2(q.z, q.w, H.u[3], L.u[3]);
    hi = H.v; lo = L.v;
}

// W -> frag-packed (wh2, wl2): element for (kc, nt, lane, j) is
// W[e = nt*16 + (lane&15)][k = kc*32 + (lane>>4)*8 + j], stored at
// elem offset (kc*4+nt)*512 + lane*8 + j  -> B loads are contiguous 1KB/wave.
// Also wt fp32 transpose [k][e] for exact recompute, and hist zero.
__global__ __launch_bounds__(256)
void k_wc(const float* __restrict__ W, unsigned short* __restrict__ wh2,
          unsigned short* __restrict__ wl2, float* __restrict__ wt,
          int* __restrict__ hist) {
    const int t = blockIdx.x * 256 + threadIdx.x;     // 0..16383
    if (t < NE * HSTR) hist[t] = 0;
    const int l  = t & 63;
    const int grp = t >> 6;                           // = kc*4 + nt, 0..255
    const int nt = grp & 3;
    const int kc = grp >> 2;
    const int e  = nt * 16 + (l & 15);
    const int k0 = kc * 32 + (l >> 4) * 8;

    const float4 p = *reinterpret_cast<const float4*>(W + (size_t)e * DIM + k0);
    const float4 q = *reinterpret_cast<const float4*>(W + (size_t)e * DIM + k0 + 4);
    FragU H, L;
    cvt2(p.x, p.y, H.u[0], L.u[0]);
    cvt2(p.z, p.w, H.u[1], L.u[1]);
    cvt2(q.x, q.y, H.u[2], L.u[2]);
    cvt2(q.z, q.w, H.u[3], L.u[3]);
    const size_t off = (size_t)grp * 512 + l * 8;
    *reinterpret_cast<uint4*>(wh2 + off) = H.q;
    *reinterpret_cast<uint4*>(wl2 + off) = L.q;

    wt[(size_t)(k0 + 0) * NE + e] = p.x;
    wt[(size_t)(k0 + 1) * NE + e] = p.y;
    wt[(size_t)(k0 + 2) * NE + e] = p.z;
    wt[(size_t)(k0 + 3) * NE + e] = p.w;
    wt[(size_t)(k0 + 4) * NE + e] = q.x;
    wt[(size_t)(k0 + 5) * NE + e] = q.y;
    wt[(size_t)(k0 + 6) * NE + e] = q.z;
    wt[(size_t)(k0 + 7) * NE + e] = q.w;
}

// Barrier-free K-loop: 8 free-running waves, wave w consumes k-chunks
// {win*256 + w*32 : win 0..7}. A direct from global (fp32), B from
// frag-packed wh2/wl2 (contiguous 1KB/wave). Single barrier before the
// cross-wave reduction. Then stats + in-block exact recompute for
// near-tie tokens + histogram + fast-path out write.
// Per-wave operand values and MFMA order are bit-identical to the
// round-2 LDS-staged version (absmax 0.0 preserved).
__global__ __launch_bounds__(512, 4)
void k_main(const float* __restrict__ x, const unsigned short* __restrict__ wh2,
            const unsigned short* __restrict__ wl2, const float* __restrict__ bias,
            const float* __restrict__ wt,
            float* __restrict__ logits, float* __restrict__ maxv,
            float* __restrict__ denomv, int* __restrict__ hist,
            float* __restrict__ out) {
    __shared__ float red[8][TPB][68];                 // 34816 B
    __shared__ float lbuf[TPB][68];                   //  4352 B
    __shared__ int   selS[TPB];
    __shared__ float wS[TPB];
    __shared__ short flagIdx[TPB];
    __shared__ int   flagCnt;

    const int tid = threadIdx.x;
    const int w   = tid >> 6;            // wave 0..7
    const int l   = tid & 63;
    const int t0  = blockIdx.x * TPB;
    const int m   = l & 15;              // token (A) / expert-low (B)
    const int g   = l >> 4;              // k-octet group

    if (tid == 0) flagCnt = 0;

    // A: lane reads x[t0+m][win*256 + w*32 + g*8 .. +8]
    const float* aP = x + (size_t)(t0 + m) * DIM + w * 32 + g * 8;
    // B: elem offset (kc*4+nt)*512 + l*8, kc = win*8 + w
    const unsigned short* bh = wh2 + (size_t)w * 2048 + l * 8;
    const unsigned short* bl = wl2 + (size_t)w * 2048 + l * 8;

    f32x4 accA[4], accB[4];
    #pragma unroll
    for (int nt = 0; nt < 4; ++nt)
        #pragma unroll
        for (int r = 0; r < 4; ++r) { accA[nt][r] = 0.0f; accB[nt][r] = 0.0f; }

    #pragma unroll
    for (int win = 0; win < 8; ++win) {
        const float4 p = *reinterpret_cast<const float4*>(aP + win * 256);
        const float4 q = *reinterpret_cast<const float4*>(aP + win * 256 + 4);
        uint4 BH[4], BL[4];
        #pragma unroll
        for (int nt = 0; nt < 4; ++nt) {
            BH[nt] = *reinterpret_cast<const uint4*>(
                bh + (size_t)win * 16384 + nt * 512);
            BL[nt] = *reinterpret_cast<const uint4*>(
                bl + (size_t)win * 16384 + nt * 512);
        }

        bf16x8 ah, al;
        make_frags(p, q, ah, al);

        #pragma unroll
        for (int nt = 0; nt < 4; ++nt) {
            FragU b; b.q = BH[nt];
            accA[nt] = __builtin_amdgcn_mfma_f32_16x16x32_bf16(ah, b.v, accA[nt], 0, 0, 0);
            accB[nt] = __builtin_amdgcn_mfma_f32_16x16x32_bf16(al, b.v, accB[nt], 0, 0, 0);
        }
        #pragma unroll
        for (int nt = 0; nt < 4; ++nt) {
            FragU b; b.q = BL[nt];
            accB[nt] = __builtin_amdgcn_mfma_f32_16x16x32_bf16(ah, b.v, accB[nt], 0, 0, 0);
        }
    }

    #pragma unroll
    for (int nt = 0; nt < 4; ++nt)
        #pragma unroll
        for (int r = 0; r < 4; ++r)
            red[w][g * 4 + r][nt * 16 + m] = accA[nt][r] + accB[nt][r];
    __syncthreads();

    for (int e2 = tid; e2 < TPB * NE; e2 += 512) {
        const int t = e2 >> 6, e = e2 & 63;
        float s = red[0][t][e];
        #pragma unroll
        for (int ww = 1; ww < 8; ++ww) s += red[ww][t][e];
        s += bias[e];
        logits[(size_t)(t0 + t) * NE + e] = s;
        lbuf[t][e] = s;
    }
    __syncthreads();

    #pragma unroll
    for (int tt = 0; tt < 2; ++tt) {
        const int t = w * 2 + tt;
        const float lv = lbuf[t][l];
        float v1 = lv; int i1 = l; float v2 = -INFINITY;
        #pragma unroll
        for (int off = 32; off; off >>= 1) {
            const float ov1 = __shfl_xor(v1, off);
            const int   oi1 = __shfl_xor(i1, off);
            const float ov2 = __shfl_xor(v2, off);
            if (ov1 > v1 || (ov1 == v1 && oi1 < i1)) {
                v2 = fmaxf(v1, ov2); v1 = ov1; i1 = oi1;
            } else {
                v2 = fmaxf(v2, ov1);
            }
        }
        float s = expf(lv - v1);
        #pragma unroll
        for (int off = 32; off; off >>= 1) s += __shfl_xor(s, off);
        if (l == 0) {
            const int row = t0 + t;
            maxv[row]   = v1;
            denomv[row] = s;
            selS[t]     = i1;
            wS[t]       = 1.0f / s;
            if (v1 - v2 < THETA) {
                const int ix = atomicAdd(&flagCnt, 1);
                flagIdx[ix] = (short)t;
            }
        }
    }
    __syncthreads();

    // ---- in-block exact fp32 recompute for flagged (near-tie) tokens ----
    const int nf = flagCnt;
    for (int fi = 0; fi < nf; ++fi) {
        const int tl  = flagIdx[fi];
        const int row = t0 + tl;
        // 8 waves split K: wave w covers k in [w*256, w*256+256); lane = expert
        const float* xr = x + (size_t)row * DIM + w * 256;
        const float* wb = wt + (size_t)(w * 256) * NE + l;
        float a0 = 0.0f, a1 = 0.0f;
        #pragma unroll 4
        for (int k = 0; k < 256; k += 8) {
            const float4 x0 = *reinterpret_cast<const float4*>(xr + k);
            const float4 x1 = *reinterpret_cast<const float4*>(xr + k + 4);
            a0 = fmaf(x0.x, wb[(size_t)(k + 0) * NE], a0);
            a0 = fmaf(x0.y, wb[(size_t)(k + 1) * NE], a0);
            a0 = fmaf(x0.z, wb[(size_t)(k + 2) * NE], a0);
            a0 = fmaf(x0.w, wb[(size_t)(k + 3) * NE], a0);
            a1 = fmaf(x1.x, wb[(size_t)(k + 4) * NE], a1);
            a1 = fmaf(x1.y, wb[(size_t)(k + 5) * NE], a1);
            a1 = fmaf(x1.z, wb[(size_t)(k + 6) * NE], a1);
            a1 = fmaf(x1.w, wb[(size_t)(k + 7) * NE], a1);
        }
        red[w][0][l] = a0 + a1;
        __syncthreads();
        if (w == 0) {
            float lg = bias[l];
            #pragma unroll
            for (int s2 = 0; s2 < 8; ++s2) lg += red[s2][0][l];
            logits[(size_t)row * NE + l] = lg;
            float v = lg; int idx = l;
            #pragma unroll
            for (int off = 32; off; off >>= 1) {
                const float ov = __shfl_xor(v, off);
                const int   oi = __shfl_xor(idx, off);
                if (ov > v || (ov == v && oi < idx)) { v = ov; idx = oi; }
            }
            float p = expf(lg - v);
            #pragma unroll
            for (int off = 32; off; off >>= 1) p += __shfl_xor(p, off);
            if (l == 0) {
                maxv[row]   = v;
                denomv[row] = p;
                selS[tl]    = idx;
                wS[tl]      = 1.0f / p;
            }
        }
        __syncthreads();
    }

    // ---- selection histogram: wave 0, lane = expert; padded counters ----
    if (w == 0) {
        int cnt = 0;
        #pragma unroll
        for (int t = 0; t < TPB; ++t) cnt += (selS[t] == l) ? 1 : 0;
        if (cnt) atomicAdd(&hist[l * HSTR], cnt);
    }

    // ---- fast-path out write (k_decide fixes up only on capacity overflow) --
    if (tid < TPB) {
        const int row = t0 + tid;
        const float se = (float)selS[tid];
        const float wv = wS[tid];
        const float wn = wv / (4.0f * wv + 1e-8f);
        *reinterpret_cast<float4*>(out + (size_t)row * 4) = make_float4(se, se, se, se);
        *reinterpret_cast<float4*>(out + (size_t)N_TOK * TOPK + (size_t)row * 4) =
            make_float4(wn, wn, wn, wn);
    }
}

// capacity check from hist; out already holds the fast path. Single block:
// if any expert over capacity, run the exact serial fallback.
__global__ __launch_bounds__(256)
void k_decide(const int* __restrict__ hist, const float* __restrict__ logits,
              const float* __restrict__ maxv, const float* __restrict__ denomv,
              const int* __restrict__ tc, float* __restrict__ out,
              float* __restrict__ wtmp) {
    __shared__ int flagS;
    const int tid = threadIdx.x;
    const int cap = tc[0] / TOPK;
    if (tid < NE) {
        const bool bad = (TOPK * hist[tid * HSTR] > cap);
        const unsigned long long mm = __ballot(bad);
        if (tid == 0) flagS = (mm == 0ull) ? 1 : 0;
    }
    __syncthreads();
    if (flagS) return;                 // fast path already written by k_main

    if (tid < 64) {
        const int e = tid;
        int rem = cap;
        for (int k = 0; k < TOPK; ++k) {
            for (int b = 0; b < N_TOK; ++b) {
                const float lg = logits[(size_t)b * NE + e];
                float v = (rem > 0) ? lg : -INFINITY;
                int idx = e;
                #pragma unroll
                for (int off = 32; off; off >>= 1) {
                    const float ov = __shfl_xor(v, off);
                    const int   oi = __shfl_xor(idx, off);
                    if (ov > v || (ov == v && oi < idx)) { v = ov; idx = oi; }
                }
                const bool ok = (v != -INFINITY);
                if (ok && e == idx) rem -= 1;
                const float lc = __shfl(lg, idx);
                if (e == 0) {
                    out[(size_t)b * TOPK + k]  = ok ? (float)idx : -1.0f;
                    wtmp[(size_t)b * TOPK + k] = ok ? expf(lc - maxv[b]) / denomv[b] : 0.0f;
                }
            }
        }
    }
    __syncthreads();
    for (int b = tid; b < N_TOK; b += 256) {
        const float w0 = wtmp[b * 4 + 0], w1_ = wtmp[b * 4 + 1];
        const float w2 = wtmp[b * 4 + 2], w3 = wtmp[b * 4 + 3];
        const float s = ((w0 + w1_) + w2) + w3 + 1e-8f;
        out[N_TOK * TOPK + b * 4 + 0] = w0 / s;
        out[N_TOK * TOPK + b * 4 + 1] = w1_ / s;
        out[N_TOK * TOPK + b * 4 + 2] = w2 / s;
        out[N_TOK * TOPK + b * 4 + 3] = w3 / s;
    }
}

extern "C" void kernel_launch(void* const* d_in, const int* in_sizes, int n_in,
                              void* d_out, int out_size, void* d_ws, size_t ws_size,
                              hipStream_t stream) {
    const float* x    = (const float*)d_in[0];
    const float* W    = (const float*)d_in[1];
    const float* bias = (const float*)d_in[2];
    const int*   tc   = (const int*)d_in[3];

    float* ws       = (float*)d_ws;
    float* logits   = ws + OFF_LOGITS;
    float* maxv     = ws + OFF_MAXV;
    float* denomv   = ws + OFF_DENOM;
    int*   hist     = (int*)(ws + OFF_HIST);
    unsigned short* wh2 = (unsigned short*)(ws + OFF_WH);
    unsigned short* wl2 = (unsigned short*)(ws + OFF_WL);
    float* wt       = ws + OFF_WT;
    float* wtmp     = ws + OFF_WTMP;
    float* out      = (float*)d_out;

    k_wc<<<NE * DIM / 8 / 256, 256, 0, stream>>>(W, wh2, wl2, wt, hist);
    k_main<<<NBLK, 512, 0, stream>>>(x, wh2, wl2, bias, wt, logits, maxv,
                                     denomv, hist, out);
    k_decide<<<1, 256, 0, stream>>>(hist, logits, maxv, denomv, tc, out, wtmp);
}